// Round 1
// 468.074 us; speedup vs baseline: 1.0900x; 1.0900x over previous
//
#include <hip/hip_runtime.h>
#include <hip/hip_bf16.h>

typedef float f32x4 __attribute__((ext_vector_type(4)));
typedef __bf16 bf16x8 __attribute__((ext_vector_type(8)));
typedef __bf16 bf16x4 __attribute__((ext_vector_type(4)));
typedef unsigned int u32;
typedef const __attribute__((address_space(1))) u32* gas_u32;
typedef __attribute__((address_space(3))) u32* las_u32;

#define NPRE (45L * 384 * 128)   // elements per transposed weight array

// ---- prep v2: LDS-transpose so BOTH sides are coalesced ----
// wpreT[k][o][i'] = w_pre[k][perm(i')][o],  perm(i') = (i'&31)*4 + (i'>>5)
// wpostT[k][s][n'][pl] = w_post[k][d(s*128+pl)][perm(n')]
//   d(p) = (p&~31) + 16*(j>>2) + 4*q + (j&3), q=(p&31)>>3, j=(p&31)&7
// Part A (bids 0..269): one (k, 64-wide o-tile) per block, transpose via LDS.
// Part B (bids 270..404): one (k, s) per block, two 64-row d-halves via LDS.
__global__ __launch_bounds__(256) void prep_weights(
    const float* __restrict__ w_pre, const float* __restrict__ w_post,
    __bf16* __restrict__ wpreT, __bf16* __restrict__ wpostT) {
  __shared__ float tile[128 * 65];   // A: [i 128][o 65pad]; B: [dl 64][i 129pad] (8256<=8320)
  const int tid = threadIdx.x;
  const int bid = blockIdx.x;
  if (bid < 270) {
    int k = bid / 6, o0 = (bid % 6) * 64;
#pragma unroll
    for (int it = 0; it < 32; ++it) {
      int i = it * 4 + (tid >> 6);
      tile[i * 65 + (tid & 63)] = w_pre[((long)(k * 128 + i)) * 384 + o0 + (tid & 63)];
    }
    __syncthreads();
#pragma unroll
    for (int it = 0; it < 8; ++it) {
      int lin = it * 256 + tid;        // (o_local 64) x (ip-quads 32)
      int ol = lin >> 5;
      int ip0 = (lin & 31) * 4;
      bf16x4 v;
#pragma unroll
      for (int jj = 0; jj < 4; ++jj) {
        int ip = ip0 + jj;
        int irow = ((ip & 31) << 2) + (ip >> 5);
        v[jj] = (__bf16)tile[irow * 65 + ol];
      }
      *(bf16x4*)(wpreT + ((long)(k * 384 + o0 + ol)) * 128 + ip0) = v;
    }
  } else {
    int r = bid - 270;
    int k = r / 3, s = r % 3;
#pragma unroll
    for (int h = 0; h < 2; ++h) {
      if (h) __syncthreads();          // half-0 readers done before overwrite
#pragma unroll
      for (int it = 0; it < 32; ++it) {
        int dl = it * 2 + (tid >> 7);  // 0..63
        int i = tid & 127;
        tile[dl * 129 + i] = w_post[((long)(k * 384 + s * 128 + h * 64 + dl)) * 128 + i];
      }
      __syncthreads();
#pragma unroll
      for (int it = 0; it < 8; ++it) {
        int lin = it * 256 + tid;      // (np 128) x (pl-quads 16)
        int np = lin >> 4;
        int pl0 = h * 64 + (lin & 15) * 4;
        int i_n = ((np & 31) << 2) + (np >> 5);
        int w0 = pl0 & 31, qq = w0 >> 3, j0 = w0 & 7;
        int dbase = (pl0 & ~31) - h * 64 + (qq << 2);
        bf16x4 v;
#pragma unroll
        for (int jj = 0; jj < 4; ++jj) {
          int j = j0 + jj;
          int dloc = dbase + ((j >> 2) << 4) + (j & 3);
          v[jj] = (__bf16)tile[dloc * 129 + i_n];
        }
        *(bf16x4*)(wpostT + (((long)(k * 3 + s)) * 128 + np) * 128 + pl0) = v;
      }
    }
  }
}

// ---- fused band MLP v2: 512 thr, 128 rows/block, pipelined half-slab dbuf ----
// 12 phases: 6x wpre halves (GEMM1) + 6x wpost halves (GEMM2). Each phase:
//   stage(p+1) -> other buffer; compute(p); __syncthreads()  (drain is covered)
// LDS 64KB => 2 blocks/CU = 16 waves/CU.
__global__ __launch_bounds__(512, 4) void band_mlp(
    const float* __restrict__ x,
    const float* __restrict__ b_pre, const float* __restrict__ b_post,
    const __bf16* __restrict__ wpreT, const __bf16* __restrict__ wpostT,
    float* __restrict__ out) {
  __shared__ __bf16 sA[128 * 128];     // 32 KB, granule-XOR-swizzled Xg tile
  __shared__ __bf16 sW2[2][64 * 128];  // 2 x 16 KB half-slab double buffer

  const int tid = threadIdx.x;
  const int bid = blockIdx.x;

  // band/tile decode: 63 tiles/band; bands 0..39 pinned to XCD k%8
  int k, tile;
  if (bid < 2520) {
    int s = bid & 7, seq = bid >> 3;
    int bi = seq / 63;
    tile = seq - bi * 63;
    k = bi * 8 + s;
  } else {
    int r = bid - 2520;
    k = 40 + r / 63;
    tile = r - (k - 40) * 63;
  }

  const int f0 = (k <= 28) ? (k * (k + 7)) / 2 : 490 + 32 * (k - 28);
  int len = (4 + k < 32) ? 4 + k : 32;
  if (len > 1025 - f0) len = 1025 - f0;

  const __bf16* wpre_k  = wpreT  + (long)k * 384 * 128;
  const __bf16* wpost_k = wpostT + (long)k * 384 * 128;

  auto stage_half = [&](int p) {       // 16KB half-slab p -> sW2[p&1]
    const __bf16* src = (p < 6 ? wpre_k : wpost_k) + (long)(p < 6 ? p : p - 6) * 8192;
    __bf16* dst = sW2[p & 1];
#pragma unroll
    for (int u = 0; u < 2; ++u) {
      int lin = u * 512 + tid;         // 16B chunk id, wave-linear dest
      int row = lin >> 4, gp = lin & 15;
      int gl = gp ^ (row & 7);
      __builtin_amdgcn_global_load_lds((gas_u32)(const void*)(src + row * 128 + gl * 8),
                                       (las_u32)(void*)(dst + lin * 8), 16, 0, 0);
    }
  };

  stage_half(0);                       // slab 0 in flight under sA staging

  // ---- stage Xg tile: 128 rows, sA[row][c*32+w] swizzled ----
  {
    const int grp = tid >> 5, l32 = tid & 31;
    for (int it = 0; it < 32; ++it) {
      int idx = it * 16 + grp;         // (row 128, c 4)
      int row = idx >> 2, c = idx & 3;
      int m = tile * 128 + row;
      int b = m / 1000, t = m - b * 1000;
      float v = (l32 < len && m < 8000)
                    ? x[((long)(b * 4 + c) * 1000 + t) * 1025 + f0 + l32] : 0.0f;
      int col = c * 32 + l32;
      int gr = (col >> 3) ^ (row & 7);
      sA[row * 128 + gr * 8 + (col & 7)] = (__bf16)v;
    }
  }

  const int lane = tid & 63;
  const int wid = tid >> 6;            // 8 waves, 16 rows each
  const int l15 = lane & 15;
  const int q = lane >> 4;
  const int m0 = wid * 16;
  const int swz = l15 & 7;

  bf16x8 hA[12];                       // H = GEMM2 A-frags, 48 VGPR

  __syncthreads();                     // sA staged + slab(0) landed (full drain, once)

  // ---- GEMM1: H = Wpre^T * Xg^T, 6 half-slab phases (4 o-tiles x K=128) ----
#pragma unroll
  for (int p = 0; p < 6; ++p) {
    const int s = p >> 1, hf = p & 1;
    stage_half(p + 1);                 // issue next half early (T3: never cold-drain)
    f32x4 bias[4];
#pragma unroll
    for (int ot = 0; ot < 4; ++ot)
      bias[ot] = *(const f32x4*)(b_pre + k * 384 + s * 128 + hf * 64 + ot * 16 + q * 4);
    f32x4 accH[4];
#pragma unroll
    for (int ot = 0; ot < 4; ++ot) accH[ot] = (f32x4){0.f, 0.f, 0.f, 0.f};
#pragma unroll
    for (int ch = 0; ch < 4; ++ch) {
      bf16x8 xb = *(const bf16x8*)(sA + (m0 + l15) * 128 + (((ch * 4 + q) ^ swz) * 8));
#pragma unroll
      for (int ot = 0; ot < 4; ++ot) {
        bf16x8 wa = *(const bf16x8*)(sW2[p & 1] + (ot * 16 + l15) * 128 + (((ch * 4 + q) ^ swz) * 8));
        accH[ot] = __builtin_amdgcn_mfma_f32_16x16x32_bf16(wa, xb, accH[ot], 0, 0, 0);
      }
    }
    // bias + pack: lane holds H[m0+l15][OT*16+q*4+r]
#pragma unroll
    for (int ot = 0; ot < 4; ++ot) {
      int OT = s * 8 + hf * 4 + ot;
#pragma unroll
      for (int r = 0; r < 4; ++r)
        hA[OT >> 1][(OT & 1) * 4 + r] = (__bf16)(accH[ot][r] + bias[ot][r]);
    }
    __syncthreads();                   // drain covered by the 16 MFMA above
  }

  // ---- GEMM2: Y = H * Wpost, 6 half-slab phases (4 n-tiles x K=128) ----
  f32x4 accY[8];
#pragma unroll
  for (int i = 0; i < 8; ++i) accY[i] = (f32x4){0.f, 0.f, 0.f, 0.f};

#pragma unroll
  for (int p = 6; p < 12; ++p) {
    const int j = (p - 6) >> 1, hf = p & 1;
    if (p < 11) stage_half(p + 1);
#pragma unroll
    for (int cl = 0; cl < 4; ++cl) {
      bf16x8 a2 = hA[j * 4 + cl];
#pragma unroll
      for (int nt = 0; nt < 4; ++nt) {
        bf16x8 wb = *(const bf16x8*)(sW2[p & 1] + (nt * 16 + l15) * 128 + (((cl * 4 + q) ^ swz) * 8));
        accY[hf * 4 + nt] = __builtin_amdgcn_mfma_f32_16x16x32_bf16(a2, wb, accY[hf * 4 + nt], 0, 0, 0);
      }
    }
    if (p < 11) __syncthreads();
  }

  // ---- epilogue: bias + scattered (64B-coalesced) stores, tail-guarded ----
  float bp[8];
#pragma unroll
  for (int nt = 0; nt < 8; ++nt) {
    int n = nt * 16 + l15;
    bp[nt] = b_post[k * 128 + ((n & 31) << 2) + (n >> 5)];
  }
  long obase[4];
  int mrow[4];
#pragma unroll
  for (int r = 0; r < 4; ++r) {
    int m = tile * 128 + m0 + q * 4 + r;
    mrow[r] = m;
    int b = m / 1000, t = m - b * 1000;
    obase[r] = (long)(b * 4) * 1025000 + (long)t * 1025 + f0;
  }
#pragma unroll
  for (int nt = 0; nt < 8; ++nt) {
    int n = nt * 16 + l15;
    int w = n & 31, c = n >> 5;
    if (w < len) {
#pragma unroll
      for (int r = 0; r < 4; ++r)
        if (mrow[r] < 8000)
          out[obase[r] + (long)c * 1025000 + w] = accY[nt][r] + bp[nt];
    }
  }
}

extern "C" void kernel_launch(void* const* d_in, const int* in_sizes, int n_in,
                              void* d_out, int out_size, void* d_ws, size_t ws_size,
                              hipStream_t stream) {
  const float* x      = (const float*)d_in[0];
  const float* w_pre  = (const float*)d_in[1];
  const float* b_pre  = (const float*)d_in[2];
  const float* w_post = (const float*)d_in[3];
  const float* b_post = (const float*)d_in[4];
  float* out = (float*)d_out;

  __bf16* wpreT  = (__bf16*)d_ws;
  __bf16* wpostT = (__bf16*)((char*)d_ws + NPRE * 2);

  prep_weights<<<405, 256, 0, stream>>>(w_pre, w_post, wpreT, wpostT);
  band_mlp<<<2835, 512, 0, stream>>>(x, b_pre, b_post, wpreT, wpostT, out);
}

// Round 3
// 386.857 us; speedup vs baseline: 1.3188x; 1.2099x over previous
//
#include <hip/hip_runtime.h>
#include <hip/hip_bf16.h>

typedef float f32x4 __attribute__((ext_vector_type(4)));
typedef __bf16 bf16x8 __attribute__((ext_vector_type(8)));
typedef __bf16 bf16x4 __attribute__((ext_vector_type(4)));
typedef unsigned int u32;
typedef const __attribute__((address_space(1))) u32* gas_u32;
typedef __attribute__((address_space(3))) u32* las_u32;

#define NPRE (45L * 384 * 128)   // elements per transposed weight array
#define X_TOT (32800L * 1025)    // total elements of x

__device__ float g_bias2[45 * 128];  // b_post + b_pre . w_post (module-static: no ws growth)

// ---- prep v3b: LDS-transpose weights + fold b_pre into g_bias2 ----
// wpreT[k][o][i'] = w_pre[k][perm(i')][o],  perm(i') = (i'&31)*4 + (i'>>5)
// wpostT[k][s][n'][pl] = w_post[k][d(s*128+pl)][perm(n')]
//   d(p) = (p&~31) + 16*(j>>2) + 4*q + (j&3), q=(p&31)>>3, j=(p&31)&7
// bias2[k][n] = b_post[k][n] + sum_d b_pre[k][d]*w_post[k][d][n]   (linearity)
__global__ __launch_bounds__(256) void prep_weights(
    const float* __restrict__ w_pre, const float* __restrict__ w_post,
    const float* __restrict__ b_pre, const float* __restrict__ b_post,
    __bf16* __restrict__ wpreT, __bf16* __restrict__ wpostT) {
  __shared__ float tile[128 * 65];   // A: [i 128][o 65pad]; B: [dl 64][i 129pad]
  const int tid = threadIdx.x;
  const int bid = blockIdx.x;
  if (bid < 270) {
    int k = bid / 6, o0 = (bid % 6) * 64;
#pragma unroll
    for (int it = 0; it < 32; ++it) {
      int i = it * 4 + (tid >> 6);
      tile[i * 65 + (tid & 63)] = w_pre[((long)(k * 128 + i)) * 384 + o0 + (tid & 63)];
    }
    __syncthreads();
#pragma unroll
    for (int it = 0; it < 8; ++it) {
      int lin = it * 256 + tid;        // (o_local 64) x (ip-quads 32)
      int ol = lin >> 5;
      int ip0 = (lin & 31) * 4;
      bf16x4 v;
#pragma unroll
      for (int jj = 0; jj < 4; ++jj) {
        int ip = ip0 + jj;
        int irow = ((ip & 31) << 2) + (ip >> 5);
        v[jj] = (__bf16)tile[irow * 65 + ol];
      }
      *(bf16x4*)(wpreT + ((long)(k * 384 + o0 + ol)) * 128 + ip0) = v;
    }
  } else if (bid < 405) {
    int r = bid - 270;
    int k = r / 3, s = r % 3;
#pragma unroll
    for (int h = 0; h < 2; ++h) {
      if (h) __syncthreads();          // half-0 readers done before overwrite
#pragma unroll
      for (int it = 0; it < 32; ++it) {
        int dl = it * 2 + (tid >> 7);  // 0..63
        int i = tid & 127;
        tile[dl * 129 + i] = w_post[((long)(k * 384 + s * 128 + h * 64 + dl)) * 128 + i];
      }
      __syncthreads();
#pragma unroll
      for (int it = 0; it < 8; ++it) {
        int lin = it * 256 + tid;      // (np 128) x (pl-quads 16)
        int np = lin >> 4;
        int pl0 = h * 64 + (lin & 15) * 4;
        int i_n = ((np & 31) << 2) + (np >> 5);
        int w0 = pl0 & 31, qq = w0 >> 3, j0 = w0 & 7;
        int dbase = (pl0 & ~31) - h * 64 + (qq << 2);
        bf16x4 v;
#pragma unroll
        for (int jj = 0; jj < 4; ++jj) {
          int j = j0 + jj;
          int dloc = dbase + ((j >> 2) << 4) + (j & 3);
          v[jj] = (__bf16)tile[dloc * 129 + i_n];
        }
        *(bf16x4*)(wpostT + (((long)(k * 3 + s)) * 128 + np) * 128 + pl0) = v;
      }
    }
  } else {
    int k = bid - 405;
    int n = tid;
    if (n < 128) {
      float acc = b_post[k * 128 + n];
      for (int d = 0; d < 384; ++d)
        acc += b_pre[k * 384 + d] * w_post[((long)k * 384 + d) * 128 + n];
      g_bias2[k * 128 + n] = acc;
    }
  }
}

// ---- fused band MLP v3b: counted-vmcnt prefetch-2 pipeline (T3+T4) ----
// Prologue: float4 x-stage -> sA; each wave hoists its xb (K=128) to regs;
// then sA's 32KB is DEAD and becomes slab bufs {0,1}; buf2 = +16KB.
// 12 half-slab phases (6 wpre + 6 wpost), 3-buffer rotation, prefetch depth 2:
//   phase p: s_waitcnt vmcnt(2) lgkmcnt(0); s_barrier  -> all waves' stage(p)
//   landed AND all waves' phase p-1 ds_reads retired (race-free, no timing
//   assumptions); then issue stage(p+2); 16 ds_read + 16 MFMA.
// vmcnt hygiene: NO other vm ops in the loop (bias folded into g_bias2).
__global__ __launch_bounds__(512, 4) void band_mlp(
    const float* __restrict__ x,
    const __bf16* __restrict__ wpreT, const __bf16* __restrict__ wpostT,
    float* __restrict__ out) {
  __shared__ __bf16 sB[3 * 64 * 128];  // 48KB: bufs{0,1} double as the 32KB sA
  __bf16* const sA = sB;

  const int tid = threadIdx.x;
  const int bid = blockIdx.x;

  // band/tile decode: 63 tiles/band; bands 0..39 pinned to XCD k%8
  int k, tile;
  if (bid < 2520) {
    int s = bid & 7, seq = bid >> 3;
    int bi = seq / 63;
    tile = seq - bi * 63;
    k = bi * 8 + s;
  } else {
    int r = bid - 2520;
    k = 40 + r / 63;
    tile = r - (k - 40) * 63;
  }

  const int f0 = (k <= 28) ? (k * (k + 7)) / 2 : 490 + 32 * (k - 28);
  int len = (4 + k < 32) ? 4 + k : 32;
  if (len > 1025 - f0) len = 1025 - f0;

  const __bf16* wpre_k  = wpreT  + (long)k * 384 * 128;
  const __bf16* wpost_k = wpostT + (long)k * 384 * 128;

  auto stage_half = [&](int p) {       // 16KB half-slab p -> sB[p%3]
    const __bf16* src = (p < 6) ? (wpre_k + (long)p * 8192)
                                : (wpost_k + (long)(p - 6) * 8192);
    __bf16* dst = sB + (p % 3) * 8192;
#pragma unroll
    for (int u = 0; u < 2; ++u) {
      int lin = u * 512 + tid;         // 16B chunk id, wave-linear dest
      int row = lin >> 4, gp = lin & 15;
      int gl = gp ^ (row & 7);
      __builtin_amdgcn_global_load_lds((gas_u32)(const void*)(src + row * 128 + gl * 8),
                                       (las_u32)(void*)(dst + lin * 8), 16, 0, 0);
    }
  };

  // ---- stage Xg tile: 128 rows, float4 loads (8 per thread), swizzled sA ----
  {
#pragma unroll
    for (int it = 0; it < 8; ++it) {
      int unit = it * 512 + tid;       // (row 128) x (c 4) x (l8 8)
      int row = unit >> 5, rem = unit & 31;
      int c = rem >> 3, l8 = rem & 7;
      int m = tile * 128 + row;
      int b = m / 1000, t = m - b * 1000;
      long gi = ((long)(b * 4 + c) * 1000 + t) * 1025 + f0 + l8 * 4;
      f32x4 v = (f32x4){0.f, 0.f, 0.f, 0.f};
      if (m < 8000) {
        if (l8 * 4 + 4 <= len && gi + 4 <= X_TOT) {
          v = *(const f32x4*)(x + gi);
        } else {
#pragma unroll
          for (int j = 0; j < 4; ++j)
            if (l8 * 4 + j < len && gi + j < X_TOT) v[j] = x[gi + j];
        }
      }
      int col0 = c * 32 + l8 * 4;
      int gr = (col0 >> 3) ^ (row & 7);
      bf16x4 bv;
#pragma unroll
      for (int j = 0; j < 4; ++j) bv[j] = (__bf16)v[j];
      *(bf16x4*)(sA + row * 128 + gr * 8 + (col0 & 7)) = bv;
    }
  }

  const int lane = tid & 63;
  const int wid = tid >> 6;            // 8 waves, 16 rows each
  const int l15 = lane & 15;
  const int q = lane >> 4;
  const int m0 = wid * 16;
  const int swz = l15 & 7;

  __syncthreads();                     // sA writes visible (full drain)

  // hoist this wave's Xg fragments: 16 VGPR, reused by all 6 GEMM1 phases
  bf16x8 xb[4];
#pragma unroll
  for (int ch = 0; ch < 4; ++ch)
    xb[ch] = *(const bf16x8*)(sA + (m0 + l15) * 128 + (((ch * 4 + q) ^ swz) * 8));

  __syncthreads();                     // all hoists complete; sA region is free

  stage_half(0);                       // fill the pipeline: depth 2
  stage_half(1);

  bf16x8 hA[12];                       // H = GEMM2 A-frags, 48 VGPR
  f32x4 accY[8];                       // GEMM2 acc; accY[0..3] doubles as GEMM1 acc

#pragma unroll
  for (int p = 0; p < 12; ++p) {
    if (p == 11) asm volatile("s_waitcnt vmcnt(0) lgkmcnt(0)" ::: "memory");
    else         asm volatile("s_waitcnt vmcnt(2) lgkmcnt(0)" ::: "memory");
    __builtin_amdgcn_s_barrier();      // all stage(p) landed; all prior readers retired
    __builtin_amdgcn_sched_barrier(0);
    if (p < 10) stage_half(p + 2);     // keep 2 slabs in flight across the barrier
    const __bf16* buf = sB + (p % 3) * 8192;
    if (p < 6) {
      // GEMM1 phase: o-rows p*64..p*64+63, K=128 from hoisted xb
#pragma unroll
      for (int ot = 0; ot < 4; ++ot) accY[ot] = (f32x4){0.f, 0.f, 0.f, 0.f};
#pragma unroll
      for (int ch = 0; ch < 4; ++ch) {
#pragma unroll
        for (int ot = 0; ot < 4; ++ot) {
          bf16x8 wa = *(const bf16x8*)(buf + (ot * 16 + l15) * 128 + (((ch * 4 + q) ^ swz) * 8));
          accY[ot] = __builtin_amdgcn_mfma_f32_16x16x32_bf16(wa, xb[ch], accY[ot], 0, 0, 0);
        }
      }
      // pack into A-frag registers: lane holds H[m0+l15][OT*16+q*4+r]
#pragma unroll
      for (int ot = 0; ot < 4; ++ot) {
        int OT = p * 4 + ot;
#pragma unroll
        for (int r = 0; r < 4; ++r)
          hA[OT >> 1][(OT & 1) * 4 + r] = (__bf16)accY[ot][r];
      }
    } else {
      // GEMM2 phase: n'-half hf of d-slice s2, A straight from hA
      const int pm = p - 6, s2 = pm >> 1, hf = pm & 1;
#pragma unroll
      for (int cl = 0; cl < 4; ++cl) {
        bf16x8 a2 = hA[s2 * 4 + cl];
#pragma unroll
        for (int nt = 0; nt < 4; ++nt) {
          bf16x8 wb = *(const bf16x8*)(buf + (nt * 16 + l15) * 128 + (((cl * 4 + q) ^ swz) * 8));
          f32x4 cin = (s2 == 0 && cl == 0) ? (f32x4){0.f, 0.f, 0.f, 0.f}
                                           : accY[hf * 4 + nt];
          accY[hf * 4 + nt] = __builtin_amdgcn_mfma_f32_16x16x32_bf16(a2, wb, cin, 0, 0, 0);
        }
      }
    }
  }

  // ---- epilogue: bias2 + scattered (64B-coalesced) stores, tail-guarded ----
  float bp[8];
#pragma unroll
  for (int nt = 0; nt < 8; ++nt) {
    int n = nt * 16 + l15;
    bp[nt] = g_bias2[k * 128 + ((n & 31) << 2) + (n >> 5)];
  }
  long obase[4];
  int mrow[4];
#pragma unroll
  for (int r = 0; r < 4; ++r) {
    int m = tile * 128 + m0 + q * 4 + r;
    mrow[r] = m;
    int b = m / 1000, t = m - b * 1000;
    obase[r] = (long)(b * 4) * 1025000 + (long)t * 1025 + f0;
  }
#pragma unroll
  for (int nt = 0; nt < 8; ++nt) {
    int n = nt * 16 + l15;
    int w = n & 31, c = n >> 5;
    if (w < len) {
#pragma unroll
      for (int r = 0; r < 4; ++r)
        if (mrow[r] < 8000)
          out[obase[r] + (long)c * 1025000 + w] = accY[nt][r] + bp[nt];
    }
  }
}

extern "C" void kernel_launch(void* const* d_in, const int* in_sizes, int n_in,
                              void* d_out, int out_size, void* d_ws, size_t ws_size,
                              hipStream_t stream) {
  const float* x      = (const float*)d_in[0];
  const float* w_pre  = (const float*)d_in[1];
  const float* b_pre  = (const float*)d_in[2];
  const float* w_post = (const float*)d_in[3];
  const float* b_post = (const float*)d_in[4];
  float* out = (float*)d_out;

  __bf16* wpreT  = (__bf16*)d_ws;
  __bf16* wpostT = (__bf16*)((char*)d_ws + NPRE * 2);

  prep_weights<<<450, 256, 0, stream>>>(w_pre, w_post, b_pre, b_post, wpreT, wpostT);
  band_mlp<<<2835, 512, 0, stream>>>(x, wpreT, wpostT, out);
}